// Round 6
// baseline (661.715 us; speedup 1.0000x reference)
//
#include <hip/hip_runtime.h>

#define N_NODES 200000
#define N_EDGES 1000000
#define N_GRAPHS 4096
#define F_IN 11
#define H 64

// ---------------- degree histogram over dst ----------------

__global__ void deg_kernel(const int* __restrict__ dst, int* __restrict__ deg) {
    int i = blockIdx.x * blockDim.x + threadIdx.x;
    if (i < N_EDGES) atomicAdd(&deg[dst[i]], 1);
}

// ---------------- CSR build: block scan + top scan + add + place ----------------

__global__ void scan_block_kernel(const int* __restrict__ deg, int* __restrict__ ex,
                                  int* __restrict__ bsum, float* __restrict__ dis) {
    __shared__ int sh[256];
    int i = blockIdx.x * 256 + threadIdx.x;
    int v = (i < N_NODES) ? deg[i] : 0;
    if (i < N_NODES) dis[i] = rsqrtf((float)(v + 1));   // +1 self loop
    sh[threadIdx.x] = v;
    __syncthreads();
    for (int o = 1; o < 256; o <<= 1) {
        int t = (threadIdx.x >= o) ? sh[threadIdx.x - o] : 0;
        __syncthreads();
        sh[threadIdx.x] += t;
        __syncthreads();
    }
    if (i < N_NODES) ex[i] = sh[threadIdx.x] - v;       // exclusive
    if (threadIdx.x == 255) bsum[blockIdx.x] = sh[255];
}

__global__ void scan_top_kernel(int* __restrict__ bsum, int nb) {
    __shared__ int sh[1024];
    int v = ((int)threadIdx.x < nb) ? bsum[threadIdx.x] : 0;
    sh[threadIdx.x] = v;
    __syncthreads();
    for (int o = 1; o < 1024; o <<= 1) {
        int t = ((int)threadIdx.x >= o) ? sh[threadIdx.x - o] : 0;
        __syncthreads();
        sh[threadIdx.x] += t;
        __syncthreads();
    }
    if ((int)threadIdx.x < nb) bsum[threadIdx.x] = sh[threadIdx.x] - v;
}

__global__ void scan_add_kernel(const int* __restrict__ ex, const int* __restrict__ boff,
                                int* __restrict__ row_start, int* __restrict__ cursor) {
    int i = blockIdx.x * 256 + threadIdx.x;
    if (i >= N_NODES) return;
    int r = ex[i] + boff[i >> 8];
    row_start[i] = r;
    cursor[i] = r;
    if (i == 0) row_start[N_NODES] = N_EDGES;
}

__global__ void place_kernel(const int* __restrict__ src, const int* __restrict__ dst,
                             int* __restrict__ cursor, int* __restrict__ csr) {
    int e = blockIdx.x * blockDim.x + threadIdx.x;
    if (e < N_EDGES) {
        int p = atomicAdd(&cursor[dst[e]], 1);
        csr[p] = src[e];
    }
}

// ---------------- register-tiled dense transform ----------------
// Y[row] = (X[row] @ W) * dis[row]; 64 rows/block, 256 threads, 4x4 per thread.

template <int K>
__global__ void gemm_tile_kernel(const float* __restrict__ X, const float* __restrict__ W,
                                 const float* __restrict__ dis, float* __restrict__ Y) {
    __shared__ float Xt[K][68];
    __shared__ float Ws[K][64];
    int tid = threadIdx.x;
    int rowbase = blockIdx.x * 64;

    for (int i = tid; i < K * 64; i += 256) Ws[i >> 6][i & 63] = W[i];

    if (K == 64) {
        for (int t = tid; t < 1024; t += 256) {
            int r = t >> 4;
            int kc = (t & 15) * 4;
            float4 v = *(const float4*)(X + (size_t)(rowbase + r) * 64 + kc);
            Xt[kc + 0][r] = v.x;
            Xt[kc + 1][r] = v.y;
            Xt[kc + 2][r] = v.z;
            Xt[kc + 3][r] = v.w;
        }
    } else {
        const float* base = X + (size_t)rowbase * K;
        for (int t = tid; t < (64 * K) / 4; t += 256) {
            float4 v = *(const float4*)(base + t * 4);
            float vv[4] = {v.x, v.y, v.z, v.w};
#pragma unroll
            for (int j = 0; j < 4; ++j) {
                int flat = t * 4 + j;
                int r = flat / K;
                int k = flat - r * K;
                Xt[k][r] = vv[j];
            }
        }
    }
    __syncthreads();

    int tc = (tid & 15) * 4;
    int tr = (tid >> 4) * 4;
    float a00 = 0, a01 = 0, a02 = 0, a03 = 0;
    float a10 = 0, a11 = 0, a12 = 0, a13 = 0;
    float a20 = 0, a21 = 0, a22 = 0, a23 = 0;
    float a30 = 0, a31 = 0, a32 = 0, a33 = 0;
#pragma unroll
    for (int k = 0; k < K; ++k) {
        float4 xv = *(const float4*)&Xt[k][tr];
        float4 wv = *(const float4*)&Ws[k][tc];
        a00 += xv.x * wv.x; a01 += xv.x * wv.y; a02 += xv.x * wv.z; a03 += xv.x * wv.w;
        a10 += xv.y * wv.x; a11 += xv.y * wv.y; a12 += xv.y * wv.z; a13 += xv.y * wv.w;
        a20 += xv.z * wv.x; a21 += xv.z * wv.y; a22 += xv.z * wv.z; a23 += xv.z * wv.w;
        a30 += xv.w * wv.x; a31 += xv.w * wv.y; a32 += xv.w * wv.z; a33 += xv.w * wv.w;
    }
    float acc[4][4] = {{a00, a01, a02, a03}, {a10, a11, a12, a13},
                       {a20, a21, a22, a23}, {a30, a31, a32, a33}};
#pragma unroll
    for (int i = 0; i < 4; ++i) {
        int row = rowbase + tr + i;
        float d = dis[row];
        float4 o;
        o.x = acc[i][0] * d; o.y = acc[i][1] * d; o.z = acc[i][2] * d; o.w = acc[i][3] * d;
        *(float4*)(Y + (size_t)row * 64 + tc) = o;
    }
}

// ---------------- CSR gather, 4 source rows in flight per wave ----------------
// lane = g*16 + q : g = edge-slot group (0..3), q = float4 feature quad (0..15).
// slot 0 = self loop (src = n), slots 1.. = csr edges. Butterfly over g at end.
// A[n] = act( dis[n] * sum_slots Bs[src] + bias )   (Bs rows already * dis[src])

template <bool RELU>
__global__ void gather_kernel(const int* __restrict__ row_start, const int* __restrict__ csr,
                              const float* __restrict__ Bs, const float* __restrict__ dis,
                              const float* __restrict__ bias, float* __restrict__ A) {
    int lane = threadIdx.x & 63;
    int q = lane & 15;
    int g = lane >> 4;
    int wave = (blockIdx.x * blockDim.x + threadIdx.x) >> 6;
    int nw = (gridDim.x * blockDim.x) >> 6;
    float4 bi = ((const float4*)bias)[q];
    for (int n = wave; n < N_NODES; n += nw) {
        int e0 = row_start[n], e1 = row_start[n + 1];
        int nslots = e1 - e0 + 1;
        float4 acc = {0.f, 0.f, 0.f, 0.f};
        for (int base = 0; base < nslots; base += 4) {
            int slot = base + g;
            if (slot < nslots) {
                int s = (slot == 0) ? n : csr[e0 + slot - 1];
                float4 v = *(const float4*)(Bs + (size_t)s * H + q * 4);
                acc.x += v.x; acc.y += v.y; acc.z += v.z; acc.w += v.w;
            }
        }
#pragma unroll
        for (int m = 16; m <= 32; m <<= 1) {
            acc.x += __shfl_xor(acc.x, m, 64);
            acc.y += __shfl_xor(acc.y, m, 64);
            acc.z += __shfl_xor(acc.z, m, 64);
            acc.w += __shfl_xor(acc.w, m, 64);
        }
        if (g == 0) {
            float d = dis[n];
            float4 o;
            o.x = acc.x * d + bi.x; o.y = acc.y * d + bi.y;
            o.z = acc.z * d + bi.z; o.w = acc.w * d + bi.w;
            if (RELU) {
                o.x = fmaxf(o.x, 0.f); o.y = fmaxf(o.y, 0.f);
                o.z = fmaxf(o.z, 0.f); o.w = fmaxf(o.w, 0.f);
            }
            *(float4*)(A + (size_t)n * H + q * 4) = o;
        }
    }
}

// layer-3 gather with fused mean-pool accumulation (no relu)
__global__ void gather_pool_kernel(const int* __restrict__ row_start, const int* __restrict__ csr,
                                   const float* __restrict__ Bs, const float* __restrict__ dis,
                                   const float* __restrict__ bias, const int* __restrict__ batch,
                                   float* __restrict__ sums, int* __restrict__ cnts) {
    int lane = threadIdx.x & 63;
    int q = lane & 15;
    int g = lane >> 4;
    int wave = (blockIdx.x * blockDim.x + threadIdx.x) >> 6;
    int nw = (gridDim.x * blockDim.x) >> 6;
    float4 bi = ((const float4*)bias)[q];
    for (int n = wave; n < N_NODES; n += nw) {
        int e0 = row_start[n], e1 = row_start[n + 1];
        int nslots = e1 - e0 + 1;
        float4 acc = {0.f, 0.f, 0.f, 0.f};
        for (int base = 0; base < nslots; base += 4) {
            int slot = base + g;
            if (slot < nslots) {
                int s = (slot == 0) ? n : csr[e0 + slot - 1];
                float4 v = *(const float4*)(Bs + (size_t)s * H + q * 4);
                acc.x += v.x; acc.y += v.y; acc.z += v.z; acc.w += v.w;
            }
        }
#pragma unroll
        for (int m = 16; m <= 32; m <<= 1) {
            acc.x += __shfl_xor(acc.x, m, 64);
            acc.y += __shfl_xor(acc.y, m, 64);
            acc.z += __shfl_xor(acc.z, m, 64);
            acc.w += __shfl_xor(acc.w, m, 64);
        }
        if (g == 0) {
            float d = dis[n];
            int bg = batch[n];
            float* sp = sums + (size_t)bg * H + q * 4;
            atomicAdd(sp + 0, acc.x * d + bi.x);
            atomicAdd(sp + 1, acc.y * d + bi.y);
            atomicAdd(sp + 2, acc.z * d + bi.z);
            atomicAdd(sp + 3, acc.w * d + bi.w);
            if (q == 0) atomicAdd(&cnts[bg], 1);
        }
    }
}

// ---------------- head ----------------

__global__ void head_kernel(const float* __restrict__ sums, const int* __restrict__ cnts,
                            const float* __restrict__ lw, const float* __restrict__ lb,
                            float* __restrict__ out) {
    int lane = threadIdx.x & 63;
    int g = (blockIdx.x * blockDim.x + threadIdx.x) >> 6;
    if (g >= N_GRAPHS) return;
    float v = sums[g * H + lane] * lw[lane];
#pragma unroll
    for (int o = 32; o; o >>= 1) v += __shfl_down(v, o, 64);
    if (lane == 0) {
        float c = (float)cnts[g];
        out[g] = v / fmaxf(c, 1.f) + lb[0];
    }
}

extern "C" void kernel_launch(void* const* d_in, const int* in_sizes, int n_in,
                              void* d_out, int out_size, void* d_ws, size_t ws_size,
                              hipStream_t stream) {
    const float* x     = (const float*)d_in[0];
    const int*   ei    = (const int*)d_in[1];
    const int*   batch = (const int*)d_in[2];
    const float* W1    = (const float*)d_in[3];
    const float* b1    = (const float*)d_in[4];
    const float* W2    = (const float*)d_in[5];
    const float* b2    = (const float*)d_in[6];
    const float* W3    = (const float*)d_in[7];
    const float* b3    = (const float*)d_in[8];
    const float* lw    = (const float*)d_in[9];
    const float* lb    = (const float*)d_in[10];
    float* out = (float*)d_out;

    const int* src = ei;
    const int* dst = ei + N_EDGES;

    const size_t NH = (size_t)N_NODES * H;
    char* ws = (char*)d_ws;
    float* A         = (float*)ws;                                    // 51.2 MB
    float* Bs        = (float*)(ws + NH * 4);                         // 51.2 MB
    float* dis       = (float*)(ws + 2 * NH * 4);                     // 0.8 MB
    int*   row_start = (int*)(ws + 2 * NH * 4 + (size_t)N_NODES * 4); // 0.8 MB (+1)
    int*   csr       = (int*)((char*)row_start + ((size_t)N_NODES + 1) * 4); // 4 MB
    float* sums      = (float*)((char*)csr + (size_t)N_EDGES * 4);    // 1 MB
    int*   cnts      = (int*)((char*)sums + (size_t)N_GRAPHS * H * 4); // 16 KB
    // transients aliased into A (A first written after CSR build completes)
    int*   deg    = (int*)A;
    int*   ex     = (int*)((char*)A + (size_t)N_NODES * 4);
    int*   cursor = (int*)((char*)A + 2 * (size_t)N_NODES * 4);
    int*   bsum   = (int*)((char*)A + 3 * (size_t)N_NODES * 4);

    const int BT = 256;
    const int NB_NODES = (N_NODES + 255) / 256;          // 782
    const int gemm_grid = N_NODES / 64;                  // 3125 (exact)
    const int gath_grid = 2048;

    // ---- CSR build + normalization ----
    hipMemsetAsync(deg, 0, (size_t)N_NODES * 4, stream);
    deg_kernel<<<(N_EDGES + BT - 1) / BT, BT, 0, stream>>>(dst, deg);
    scan_block_kernel<<<NB_NODES, 256, 0, stream>>>(deg, ex, bsum, dis);
    scan_top_kernel<<<1, 1024, 0, stream>>>(bsum, NB_NODES);
    scan_add_kernel<<<NB_NODES, 256, 0, stream>>>(ex, bsum, row_start, cursor);
    place_kernel<<<(N_EDGES + BT - 1) / BT, BT, 0, stream>>>(src, dst, cursor, csr);

    // ---- layer 1 ----
    gemm_tile_kernel<F_IN><<<gemm_grid, BT, 0, stream>>>(x, W1, dis, Bs);
    gather_kernel<true><<<gath_grid, BT, 0, stream>>>(row_start, csr, Bs, dis, b1, A);

    // ---- layer 2 ----
    gemm_tile_kernel<H><<<gemm_grid, BT, 0, stream>>>(A, W2, dis, Bs);
    gather_kernel<true><<<gath_grid, BT, 0, stream>>>(row_start, csr, Bs, dis, b2, A);

    // ---- layer 3 + fused mean pool ----
    gemm_tile_kernel<H><<<gemm_grid, BT, 0, stream>>>(A, W3, dis, Bs);
    hipMemsetAsync(sums, 0, (size_t)N_GRAPHS * H * 4 + (size_t)N_GRAPHS * 4, stream);
    gather_pool_kernel<<<gath_grid, BT, 0, stream>>>(row_start, csr, Bs, dis, b3, batch,
                                                     sums, cnts);

    // ---- head ----
    head_kernel<<<(N_GRAPHS * 64 + BT - 1) / BT, BT, 0, stream>>>(sums, cnts, lw, lb, out);
}

// Round 7
// 497.893 us; speedup vs baseline: 1.3290x; 1.3290x over previous
//
#include <hip/hip_runtime.h>

#define N_NODES 200000
#define N_EDGES 1000000
#define N_GRAPHS 4096
#define F_IN 11
#define H 64

// ---------------- degree histogram over dst ----------------

__global__ void deg_kernel(const int* __restrict__ dst, int* __restrict__ deg) {
    int i = blockIdx.x * blockDim.x + threadIdx.x;
    if (i < N_EDGES) atomicAdd(&deg[dst[i]], 1);
}

__global__ void batch_cnt_kernel(const int* __restrict__ batch, int* __restrict__ cnts) {
    int i = blockIdx.x * blockDim.x + threadIdx.x;
    if (i < N_NODES) atomicAdd(&cnts[batch[i]], 1);
}

// ---------------- CSR build: block scan + top scan + add + place ----------------

__global__ void scan_block_kernel(const int* __restrict__ deg, int* __restrict__ ex,
                                  int* __restrict__ bsum, float* __restrict__ dis) {
    __shared__ int sh[256];
    int i = blockIdx.x * 256 + threadIdx.x;
    int v = (i < N_NODES) ? deg[i] : 0;
    if (i < N_NODES) dis[i] = rsqrtf((float)(v + 1));   // +1 self loop
    sh[threadIdx.x] = v;
    __syncthreads();
    for (int o = 1; o < 256; o <<= 1) {
        int t = (threadIdx.x >= o) ? sh[threadIdx.x - o] : 0;
        __syncthreads();
        sh[threadIdx.x] += t;
        __syncthreads();
    }
    if (i < N_NODES) ex[i] = sh[threadIdx.x] - v;       // exclusive
    if (threadIdx.x == 255) bsum[blockIdx.x] = sh[255];
}

__global__ void scan_top_kernel(int* __restrict__ bsum, int nb) {
    __shared__ int sh[1024];
    int v = ((int)threadIdx.x < nb) ? bsum[threadIdx.x] : 0;
    sh[threadIdx.x] = v;
    __syncthreads();
    for (int o = 1; o < 1024; o <<= 1) {
        int t = ((int)threadIdx.x >= o) ? sh[threadIdx.x - o] : 0;
        __syncthreads();
        sh[threadIdx.x] += t;
        __syncthreads();
    }
    if ((int)threadIdx.x < nb) bsum[threadIdx.x] = sh[threadIdx.x] - v;
}

__global__ void scan_add_kernel(const int* __restrict__ ex, const int* __restrict__ boff,
                                int* __restrict__ row_start, int* __restrict__ cursor) {
    int i = blockIdx.x * 256 + threadIdx.x;
    if (i >= N_NODES) return;
    int r = ex[i] + boff[i >> 8];
    row_start[i] = r;
    cursor[i] = r;
    if (i == 0) row_start[N_NODES] = N_EDGES;
}

__global__ void place_kernel(const int* __restrict__ src, const int* __restrict__ dst,
                             int* __restrict__ cursor, int* __restrict__ csr) {
    int e = blockIdx.x * blockDim.x + threadIdx.x;
    if (e < N_EDGES) {
        int p = atomicAdd(&cursor[dst[e]], 1);
        csr[p] = src[e];
    }
}

// ---------------- xs = x * dis[row]  (layer-1 pre-scale, 11-wide) ----------------

__global__ void xscale_kernel(const float* __restrict__ x, const float* __restrict__ dis,
                              float* __restrict__ xs) {
    int i = blockIdx.x * blockDim.x + threadIdx.x;
    if (i < N_NODES * F_IN) {
        int row = i / F_IN;
        xs[i] = x[i] * dis[row];
    }
}

// ---------------- layer-1 gather on 11-wide xs: P[n] = dis[n]*(sum_src xs + xs[n]) ----
// 4 nodes per wave: u = lane>>4 node sub-index, c = lane&15 feature (active c<11).

__global__ void gather1_kernel(const int* __restrict__ row_start, const int* __restrict__ csr,
                               const float* __restrict__ xs, const float* __restrict__ dis,
                               float* __restrict__ P) {
    int lane = threadIdx.x & 63;
    int c = lane & 15;
    int u = lane >> 4;
    int wave = (blockIdx.x * blockDim.x + threadIdx.x) >> 6;
    int nw = (gridDim.x * blockDim.x) >> 6;
    for (int n4 = wave * 4; n4 < N_NODES; n4 += nw * 4) {
        int n = n4 + u;
        int e0 = row_start[n], e1 = row_start[n + 1];
        float acc = xs[(size_t)n * F_IN + c % F_IN];   // self (c>=11 lanes harmless dup)
        int e = e0;
        for (; e + 4 <= e1; e += 4) {
            int s0 = csr[e], s1 = csr[e + 1], s2 = csr[e + 2], s3 = csr[e + 3];
            float v0 = xs[(size_t)s0 * F_IN + c];
            float v1 = xs[(size_t)s1 * F_IN + c];
            float v2 = xs[(size_t)s2 * F_IN + c];
            float v3 = xs[(size_t)s3 * F_IN + c];
            acc += (v0 + v1) + (v2 + v3);
        }
        for (; e < e1; ++e) acc += xs[(size_t)csr[e] * F_IN + c];
        if (c < F_IN) P[(size_t)n * F_IN + c] = acc * dis[n];
    }
}

// ---------------- register-tiled dense transform ----------------
// 64 rows/block, 256 threads, 4x4 per thread.
// DIS_OUT: Y = (X@W)*dis[row] (no bias). BIAS_RELU: Y = relu(X@W + bias).

template <int K, bool DIS_OUT, bool BIAS_RELU>
__global__ void gemm_tile_kernel(const float* __restrict__ X, const float* __restrict__ W,
                                 const float* __restrict__ dis, const float* __restrict__ bias,
                                 float* __restrict__ Y) {
    __shared__ float Xt[K][68];
    __shared__ float Ws[K][64];
    int tid = threadIdx.x;
    int rowbase = blockIdx.x * 64;

    for (int i = tid; i < K * 64; i += 256) Ws[i >> 6][i & 63] = W[i];

    if (K == 64) {
        for (int t = tid; t < 1024; t += 256) {
            int r = t >> 4;
            int kc = (t & 15) * 4;
            float4 v = *(const float4*)(X + (size_t)(rowbase + r) * 64 + kc);
            Xt[kc + 0][r] = v.x;
            Xt[kc + 1][r] = v.y;
            Xt[kc + 2][r] = v.z;
            Xt[kc + 3][r] = v.w;
        }
    } else {
        const float* base = X + (size_t)rowbase * K;
        for (int t = tid; t < (64 * K) / 4; t += 256) {
            float4 v = *(const float4*)(base + t * 4);
            float vv[4] = {v.x, v.y, v.z, v.w};
#pragma unroll
            for (int j = 0; j < 4; ++j) {
                int flat = t * 4 + j;
                int r = flat / K;
                int k = flat - r * K;
                Xt[k][r] = vv[j];
            }
        }
    }
    __syncthreads();

    int tc = (tid & 15) * 4;
    int tr = (tid >> 4) * 4;
    float a00 = 0, a01 = 0, a02 = 0, a03 = 0;
    float a10 = 0, a11 = 0, a12 = 0, a13 = 0;
    float a20 = 0, a21 = 0, a22 = 0, a23 = 0;
    float a30 = 0, a31 = 0, a32 = 0, a33 = 0;
#pragma unroll
    for (int k = 0; k < K; ++k) {
        float4 xv = *(const float4*)&Xt[k][tr];
        float4 wv = *(const float4*)&Ws[k][tc];
        a00 += xv.x * wv.x; a01 += xv.x * wv.y; a02 += xv.x * wv.z; a03 += xv.x * wv.w;
        a10 += xv.y * wv.x; a11 += xv.y * wv.y; a12 += xv.y * wv.z; a13 += xv.y * wv.w;
        a20 += xv.z * wv.x; a21 += xv.z * wv.y; a22 += xv.z * wv.z; a23 += xv.z * wv.w;
        a30 += xv.w * wv.x; a31 += xv.w * wv.y; a32 += xv.w * wv.z; a33 += xv.w * wv.w;
    }
    float acc[4][4] = {{a00, a01, a02, a03}, {a10, a11, a12, a13},
                       {a20, a21, a22, a23}, {a30, a31, a32, a33}};
    float4 bv;
    if (BIAS_RELU) bv = *(const float4*)(bias + tc);
#pragma unroll
    for (int i = 0; i < 4; ++i) {
        int row = rowbase + tr + i;
        float4 o;
        if (DIS_OUT) {
            float d = dis[row];
            o.x = acc[i][0] * d; o.y = acc[i][1] * d; o.z = acc[i][2] * d; o.w = acc[i][3] * d;
        } else {
            o.x = acc[i][0] + bv.x; o.y = acc[i][1] + bv.y;
            o.z = acc[i][2] + bv.z; o.w = acc[i][3] + bv.w;
            if (BIAS_RELU) {
                o.x = fmaxf(o.x, 0.f); o.y = fmaxf(o.y, 0.f);
                o.z = fmaxf(o.z, 0.f); o.w = fmaxf(o.w, 0.f);
            }
        }
        *(float4*)(Y + (size_t)row * 64 + tc) = o;
    }
}

// ---------------- CSR gather, slot-parallel (layer 2) ----------------
// lane = g*16 + q : g = edge-slot group (0..3), q = float4 quad (0..15).

template <bool RELU>
__global__ void gather_kernel(const int* __restrict__ row_start, const int* __restrict__ csr,
                              const float* __restrict__ Bs, const float* __restrict__ dis,
                              const float* __restrict__ bias, float* __restrict__ A) {
    int lane = threadIdx.x & 63;
    int q = lane & 15;
    int g = lane >> 4;
    int wave = (blockIdx.x * blockDim.x + threadIdx.x) >> 6;
    int nw = (gridDim.x * blockDim.x) >> 6;
    float4 bi = ((const float4*)bias)[q];
    for (int n = wave; n < N_NODES; n += nw) {
        int e0 = row_start[n], e1 = row_start[n + 1];
        int nslots = e1 - e0 + 1;
        float4 acc = {0.f, 0.f, 0.f, 0.f};
        for (int base = 0; base < nslots; base += 4) {
            int slot = base + g;
            if (slot < nslots) {
                int s = (slot == 0) ? n : csr[e0 + slot - 1];
                float4 v = *(const float4*)(Bs + (size_t)s * H + q * 4);
                acc.x += v.x; acc.y += v.y; acc.z += v.z; acc.w += v.w;
            }
        }
#pragma unroll
        for (int m = 16; m <= 32; m <<= 1) {
            acc.x += __shfl_xor(acc.x, m, 64);
            acc.y += __shfl_xor(acc.y, m, 64);
            acc.z += __shfl_xor(acc.z, m, 64);
            acc.w += __shfl_xor(acc.w, m, 64);
        }
        if (g == 0) {
            float d = dis[n];
            float4 o;
            o.x = acc.x * d + bi.x; o.y = acc.y * d + bi.y;
            o.z = acc.z * d + bi.z; o.w = acc.w * d + bi.w;
            if (RELU) {
                o.x = fmaxf(o.x, 0.f); o.y = fmaxf(o.y, 0.f);
                o.z = fmaxf(o.z, 0.f); o.w = fmaxf(o.w, 0.f);
            }
            *(float4*)(A + (size_t)n * H + q * 4) = o;
        }
    }
}

// ---------------- layer-3 gather + in-register dot(lin_w) + scalar pool ----------------
// gsum[batch[n]] += dis[n] * dot(sum_slots Bs[src], lw); bias term folded into head.

__global__ void gather_dot_pool_kernel(const int* __restrict__ row_start,
                                       const int* __restrict__ csr,
                                       const float* __restrict__ Bs,
                                       const float* __restrict__ dis,
                                       const float* __restrict__ lw,
                                       const int* __restrict__ batch,
                                       float* __restrict__ gsum) {
    int lane = threadIdx.x & 63;
    int q = lane & 15;
    int g = lane >> 4;
    int wave = (blockIdx.x * blockDim.x + threadIdx.x) >> 6;
    int nw = (gridDim.x * blockDim.x) >> 6;
    float4 lw4 = ((const float4*)lw)[q];
    for (int n = wave; n < N_NODES; n += nw) {
        int e0 = row_start[n], e1 = row_start[n + 1];
        int nslots = e1 - e0 + 1;
        float4 acc = {0.f, 0.f, 0.f, 0.f};
        for (int base = 0; base < nslots; base += 4) {
            int slot = base + g;
            if (slot < nslots) {
                int s = (slot == 0) ? n : csr[e0 + slot - 1];
                float4 v = *(const float4*)(Bs + (size_t)s * H + q * 4);
                acc.x += v.x; acc.y += v.y; acc.z += v.z; acc.w += v.w;
            }
        }
        // partial dot in every lane, then full-wave butterfly over all 64 lanes
        float p = acc.x * lw4.x + acc.y * lw4.y + acc.z * lw4.z + acc.w * lw4.w;
#pragma unroll
        for (int m = 1; m <= 32; m <<= 1) p += __shfl_xor(p, m, 64);
        if (lane == 0) atomicAdd(&gsum[batch[n]], p * dis[n]);
    }
}

// ---------------- head: out[g] = gsum/cnt + dot(b3,lw) + lb ----------------

__global__ void head2_kernel(const float* __restrict__ gsum, const int* __restrict__ cnts,
                             const float* __restrict__ b3, const float* __restrict__ lw,
                             const float* __restrict__ lb, float* __restrict__ out) {
    int g = blockIdx.x * blockDim.x + threadIdx.x;
    if (g >= N_GRAPHS) return;
    float cb = 0.f;
#pragma unroll
    for (int k = 0; k < H; ++k) cb += b3[k] * lw[k];
    int c = cnts[g];
    out[g] = (c > 0) ? (gsum[g] / (float)c + cb + lb[0]) : lb[0];
}

extern "C" void kernel_launch(void* const* d_in, const int* in_sizes, int n_in,
                              void* d_out, int out_size, void* d_ws, size_t ws_size,
                              hipStream_t stream) {
    const float* x     = (const float*)d_in[0];
    const int*   ei    = (const int*)d_in[1];
    const int*   batch = (const int*)d_in[2];
    const float* W1    = (const float*)d_in[3];
    const float* b1    = (const float*)d_in[4];
    const float* W2    = (const float*)d_in[5];
    const float* b2    = (const float*)d_in[6];
    const float* W3    = (const float*)d_in[7];
    const float* b3    = (const float*)d_in[8];
    const float* lw    = (const float*)d_in[9];
    const float* lb    = (const float*)d_in[10];
    float* out = (float*)d_out;

    const int* src = ei;
    const int* dst = ei + N_EDGES;

    const size_t NH = (size_t)N_NODES * H;
    char* ws = (char*)d_ws;
    float* A         = (float*)ws;                                    // 51.2 MB (h1/h2)
    float* Bs        = (float*)(ws + NH * 4);                         // 51.2 MB
    float* dis       = (float*)(ws + 2 * NH * 4);                     // 0.8 MB
    int*   row_start = (int*)(ws + 2 * NH * 4 + (size_t)N_NODES * 4); // 0.8 MB (+1)
    int*   csr       = (int*)((char*)row_start + ((size_t)N_NODES + 1) * 4); // 4 MB
    float* gsum      = (float*)((char*)csr + (size_t)N_EDGES * 4);    // 16 KB
    int*   cnts      = (int*)((char*)gsum + (size_t)N_GRAPHS * 4);    // 16 KB
    // layer-1 transients inside Bs region (consumed before Bs is overwritten)
    float* xs = Bs;                                    // 8.8 MB
    float* P  = (float*)((char*)Bs + (16u << 20));     // 8.8 MB at +16 MB
    // CSR-build transients aliased into A (A first written by gemm1, after build)
    int*   deg    = (int*)A;
    int*   ex     = (int*)((char*)A + (size_t)N_NODES * 4);
    int*   cursor = (int*)((char*)A + 2 * (size_t)N_NODES * 4);
    int*   bsum   = (int*)((char*)A + 3 * (size_t)N_NODES * 4);

    const int BT = 256;
    const int NB_NODES = (N_NODES + 255) / 256;          // 782
    const int gemm_grid = N_NODES / 64;                  // 3125 (exact)
    const int gath_grid = 2048;

    // ---- CSR build + normalization + batch histogram ----
    hipMemsetAsync(deg, 0, (size_t)N_NODES * 4, stream);
    hipMemsetAsync(gsum, 0, (size_t)N_GRAPHS * 8, stream);   // gsum + cnts
    deg_kernel<<<(N_EDGES + BT - 1) / BT, BT, 0, stream>>>(dst, deg);
    batch_cnt_kernel<<<NB_NODES, BT, 0, stream>>>(batch, cnts);
    scan_block_kernel<<<NB_NODES, 256, 0, stream>>>(deg, ex, bsum, dis);
    scan_top_kernel<<<1, 1024, 0, stream>>>(bsum, NB_NODES);
    scan_add_kernel<<<NB_NODES, 256, 0, stream>>>(ex, bsum, row_start, cursor);
    place_kernel<<<(N_EDGES + BT - 1) / BT, BT, 0, stream>>>(src, dst, cursor, csr);

    // ---- layer 1 (aggregate-first on 11-wide, then fused GEMM+bias+relu) ----
    xscale_kernel<<<(N_NODES * F_IN + BT - 1) / BT, BT, 0, stream>>>(x, dis, xs);
    gather1_kernel<<<gath_grid, BT, 0, stream>>>(row_start, csr, xs, dis, P);
    gemm_tile_kernel<F_IN, false, true><<<gemm_grid, BT, 0, stream>>>(P, W1, dis, b1, A);

    // ---- layer 2 ----
    gemm_tile_kernel<H, true, false><<<gemm_grid, BT, 0, stream>>>(A, W2, dis, b2, Bs);
    gather_kernel<true><<<gath_grid, BT, 0, stream>>>(row_start, csr, Bs, dis, b2, A);

    // ---- layer 3: GEMM then gather+dot+pool (scalar atomics only) ----
    gemm_tile_kernel<H, true, false><<<gemm_grid, BT, 0, stream>>>(A, W3, dis, b3, Bs);
    gather_dot_pool_kernel<<<gath_grid, BT, 0, stream>>>(row_start, csr, Bs, dis, lw,
                                                         batch, gsum);

    // ---- head ----
    head2_kernel<<<(N_GRAPHS + BT - 1) / BT, BT, 0, stream>>>(gsum, cnts, b3, lw, lb, out);
}